// Round 8
// baseline (160.864 us; speedup 1.0000x reference)
//
#include <hip/hip_runtime.h>
#include <math.h>

#define NPOS 512
#define DIM  512
#define NB   1024
#define EPSV 1e-5f
#define COS_EPS 1e-8f

// ws float offsets
#define OFF_INV 0                      // [1024] inv norms, allv order [pos;neg]
#define OFF_T1  1024                   // [512]  pos . w1
#define OFF_T2  1536                   // [1024] allv . w2
#define OFF_S   2560                   // [512*1024] RAW cos dots (cols = allv m)
#define PSZ     (NPOS * NB)            // 524288
#define OFF_TP  (OFF_S + PSZ)          // 8 x PSZ t3 partials (z = 0..7)
#define OFF_BAR (OFF_TP + 8 * PSZ)     // barrier counter (poisoned to 0xAAAAAAAA)
#define BAR_TARGET (0xAAAAAAAAu + 512u)

#define FSW(x) ((x) + 4 * ((x) >> 5))

typedef __attribute__((ext_vector_type(8))) __bf16 bf16x8;
typedef __attribute__((ext_vector_type(4))) float  f32x4;

__device__ __forceinline__ float softplus_f(float x) {
    return fmaxf(x, 0.f) + __logf(1.f + __expf(-fabsf(x)));
}

__device__ __forceinline__ unsigned f2bf2(float lo, float hi) {
    union { float f; unsigned u; } a, b; a.f = lo; b.f = hi;
    unsigned x = (a.u + 0x7fffu + ((a.u >> 16) & 1u)) >> 16;
    unsigned y = (b.u + 0x7fffu + ((b.u >> 16) & 1u)) >> 16;
    return x | (y << 16);
}

// ====================== single fused kernel, 512 blocks ======================
// phase 1 (per block): t3 tile (64n x 128m, k-split 8) + 4 cos MFMA tiles
//                      + 2 prep rows. phase 2 (after device barrier): finish.
__global__ __launch_bounds__(256, 2) void mono_kernel(
    const float* __restrict__ pos, const float* __restrict__ neg,
    const float* __restrict__ w, const float* __restrict__ lb,
    float* __restrict__ ws, float* __restrict__ out)
{
    __shared__ __align__(16) float sh[13384];
    float* Asf = sh;            // [64][68] k-major A
    float* Bsf = sh + 4352;     // [64][140] k-major B (FSW cols)
    float* wls = sh + 13312;    // [64] w3 slice
    float* fin = sh + 13376;    // [8] finish scratch

    const int b   = blockIdx.x;
    const int tid = threadIdx.x;
    const int wvid = tid >> 6;
    const int lane = tid & 63;

    if (b == 0 && tid == 0) out[0] = 0.f;

    // ---------------- phase 1a: t3 tile ----------------
    const int z  = b >> 6;
    const int bb = b & 63;
    const int n0 = (bb >> 3) * 64;
    const int m0 = (bb & 7) * 128;
    const int kb = z * 64;

    const float* Asrc = pos + (size_t)n0 * DIM + kb;
    const float* Bsrc = ((m0 < NPOS) ? (pos + (size_t)m0 * DIM)
                                     : (neg + (size_t)(m0 - NPOS) * DIM)) + kb;
    const float* w3g = w + 2 * DIM + kb;

    // stage A (k-major): lane-distinct n, wave-fixed k-base -> 2-way write banks
    {
        const int n = tid & 63;
        const int g = (tid >> 6) * 16;
        #pragma unroll
        for (int u = 0; u < 4; ++u) {
            float4 v = *(const float4*)(Asrc + (size_t)n * DIM + g + 4 * u);
            Asf[(g + 4 * u + 0) * 68 + n] = v.x;
            Asf[(g + 4 * u + 1) * 68 + n] = v.y;
            Asf[(g + 4 * u + 2) * 68 + n] = v.z;
            Asf[(g + 4 * u + 3) * 68 + n] = v.w;
        }
    }
    // stage B (k-major, FSW col swizzle): 2-way write banks
    {
        const int r = tid >> 1, h = (tid & 1) * 32;
        const int fr = FSW(r);
        #pragma unroll
        for (int u = 0; u < 8; ++u) {
            float4 v = *(const float4*)(Bsrc + (size_t)r * DIM + h + 4 * u);
            Bsf[(h + 4 * u + 0) * 140 + fr] = v.x;
            Bsf[(h + 4 * u + 1) * 140 + fr] = v.y;
            Bsf[(h + 4 * u + 2) * 140 + fr] = v.z;
            Bsf[(h + 4 * u + 3) * 140 + fr] = v.w;
        }
    }
    if (tid < 16) *(float4*)(wls + tid * 4) = *(const float4*)(w3g + tid * 4);
    __syncthreads();

    const int n4 = (tid & 15) * 4;
    const int m8 = (tid >> 4) * 8;
    const int fm = FSW(m8);

    float acc[4][8] = {{0.f}};

    #pragma unroll 1
    for (int k0 = 0; k0 < 64; k0 += 4) {
        const float4 wv4 = *(const float4*)(wls + k0);
        const float wk4[4] = {wv4.x, wv4.y, wv4.z, wv4.w};
        #pragma unroll
        for (int kk = 0; kk < 4; ++kk) {
            const int k = k0 + kk;
            const float4 av = *(const float4*)(Asf + k * 68 + n4);
            const float4 b0 = *(const float4*)(Bsf + k * 140 + fm);
            const float4 b1 = *(const float4*)(Bsf + k * 140 + fm + 4);
            const float wk = wk4[kk];
            const float a[4]  = {av.x, av.y, av.z, av.w};
            const float bv[8] = {b0.x, b0.y, b0.z, b0.w, b1.x, b1.y, b1.z, b1.w};
            #pragma unroll
            for (int r = 0; r < 4; ++r)
                #pragma unroll
                for (int s = 0; s < 8; ++s) {
                    float d = a[r] - bv[s];
                    asm("v_fma_f32 %0, abs(%1), %2, %0"
                        : "+v"(acc[r][s]) : "v"(d), "v"(wk));
                }
        }
    }

    {
        float* Tp = ws + OFF_TP + (size_t)z * PSZ;
        #pragma unroll
        for (int r = 0; r < 4; ++r) {
            int n = n0 + n4 + r;
            float4 o0 = {acc[r][0], acc[r][1], acc[r][2], acc[r][3]};
            float4 o1 = {acc[r][4], acc[r][5], acc[r][6], acc[r][7]};
            *(float4*)(Tp + (size_t)n * NB + m0 + m8)     = o0;
            *(float4*)(Tp + (size_t)n * NB + m0 + m8 + 4) = o1;
        }
    }

    // ---------------- phase 1b: cos MFMA tile (one 16x16 per wave) ----------------
    {
        const int W = (b << 2) | wvid;        // 0..2047
        const int cn0 = (W >> 6) << 4;        // pos-row tile
        const int cm0 = (W & 63) << 4;        // allv-row tile
        const int rc   = lane & 15;
        const int quad = lane >> 4;

        const float* arow = pos + (size_t)(cn0 + rc) * DIM + quad * 8;
        const float* brow = ((cm0 < NPOS) ? (pos + (size_t)(cm0 + rc) * DIM)
                                          : (neg + (size_t)(cm0 - NPOS + rc) * DIM)) + quad * 8;

        f32x4 cacc = {0.f, 0.f, 0.f, 0.f};
        #pragma unroll 4
        for (int k = 0; k < 16; ++k) {
            float4 a0 = *(const float4*)(arow + k * 32);
            float4 a1 = *(const float4*)(arow + k * 32 + 4);
            float4 c0 = *(const float4*)(brow + k * 32);
            float4 c1 = *(const float4*)(brow + k * 32 + 4);
            union { unsigned u[4]; bf16x8 v; } af, bf;
            af.u[0] = f2bf2(a0.x, a0.y); af.u[1] = f2bf2(a0.z, a0.w);
            af.u[2] = f2bf2(a1.x, a1.y); af.u[3] = f2bf2(a1.z, a1.w);
            bf.u[0] = f2bf2(c0.x, c0.y); bf.u[1] = f2bf2(c0.z, c0.w);
            bf.u[2] = f2bf2(c1.x, c1.y); bf.u[3] = f2bf2(c1.z, c1.w);
            cacc = __builtin_amdgcn_mfma_f32_16x16x32_bf16(af.v, bf.v, cacc, 0, 0, 0);
        }
        float* S = ws + OFF_S;
        #pragma unroll
        for (int e = 0; e < 4; ++e) {
            int n = cn0 + quad * 4 + e;            // D: col=lane&15, row=quad*4+e
            S[(size_t)n * NB + cm0 + rc] = cacc[e];
        }
    }

    // ---------------- phase 1c: prep (2 rows per block, waves 0-1) ----------------
    if (wvid < 2) {
        int row = 2 * b + wvid;                    // 0..1023, allv order
        bool is_pos = row < NPOS;
        const float* r = is_pos ? pos + (size_t)row * DIM : neg + (size_t)(row - NPOS) * DIM;
        const float4* r4  = (const float4*)r + lane * 2;
        const float4* w14 = (const float4*)(w) + lane * 2;
        const float4* w24 = (const float4*)(w + DIM) + lane * 2;
        float4 a0 = r4[0],  a1 = r4[1];
        float4 u0 = w14[0], u1 = w14[1];
        float4 v0 = w24[0], v1 = w24[1];
        float ss  = a0.x*a0.x + a0.y*a0.y + a0.z*a0.z + a0.w*a0.w
                  + a1.x*a1.x + a1.y*a1.y + a1.z*a1.z + a1.w*a1.w;
        float dw1 = a0.x*u0.x + a0.y*u0.y + a0.z*u0.z + a0.w*u0.w
                  + a1.x*u1.x + a1.y*u1.y + a1.z*u1.z + a1.w*u1.w;
        float dw2 = a0.x*v0.x + a0.y*v0.y + a0.z*v0.z + a0.w*v0.w
                  + a1.x*v1.x + a1.y*v1.y + a1.z*v1.z + a1.w*v1.w;
        #pragma unroll
        for (int off = 32; off; off >>= 1) {
            ss  += __shfl_xor(ss, off);
            dw1 += __shfl_xor(dw1, off);
            dw2 += __shfl_xor(dw2, off);
        }
        if (lane == 0) {
            float inv = 1.f / fmaxf(sqrtf(ss), COS_EPS);
            ws[OFF_INV + row] = inv;
            ws[OFF_T2 + row]  = dw2;
            if (is_pos) ws[OFF_T1 + row] = dw1;
        }
    }

    // ---------------- device barrier (poison-value counter) ----------------
    __syncthreads();
    if (tid == 0) {
        unsigned* bar = (unsigned*)(ws + OFF_BAR);
        __threadfence();                       // release: flush this block's writes
        atomicAdd(bar, 1u);
        for (int it = 0; it < (1 << 22); ++it) {
            if (atomicAdd(bar, 0u) == BAR_TARGET) break;
            __builtin_amdgcn_s_sleep(8);
        }
        __threadfence();                       // acquire: invalidate stale caches
    }
    __syncthreads();

    // ---------------- phase 2: finish (one n-row per block) ----------------
    {
        const int n  = b;
        const int wv = wvid;
        const int l  = lane;
        const int i4 = wv * 64 + l;            // float4 col index, m = 4*i4..

        const float invn = ws[OFF_INV + n];
        const float4 sraw = ((const float4*)(ws + OFF_S + (size_t)n * NB))[i4];
        const float4 inv4 = *(const float4*)(ws + OFF_INV + 4 * i4);
        float4 cc;
        cc.x = sraw.x * invn * inv4.x;
        cc.y = sraw.y * invn * inv4.y;
        cc.z = sraw.z * invn * inv4.z;
        cc.w = sraw.w * invn * inv4.w;

        float4 tt = {0.f, 0.f, 0.f, 0.f};
        #pragma unroll
        for (int zz = 0; zz < 8; ++zz) {
            const float4 p = ((const float4*)(ws + OFF_TP + (size_t)zz * PSZ + (size_t)n * NB))[i4];
            tt.x += p.x; tt.y += p.y; tt.z += p.z; tt.w += p.w;
        }

        float ep = 0.f;
        if (wv >= 2)
            ep = __expf(cc.x) + __expf(cc.y) + __expf(cc.z) + __expf(cc.w);
        #pragma unroll
        for (int off = 32; off; off >>= 1) ep += __shfl_xor(ep, off);
        if (l == 0) fin[wv] = ep;
        __syncthreads();
        const float eneg = fin[2] + fin[3];

        float part = 0.f;
        if (wv < 2) {
            part += __logf(eneg + __expf(cc.x) + EPSV) - cc.x;
            part += __logf(eneg + __expf(cc.y) + EPSV) - cc.y;
            part += __logf(eneg + __expf(cc.z) + EPSV) - cc.z;
            part += __logf(eneg + __expf(cc.w) + EPSV) - cc.w;
        }

        const float t1n  = ws[OFF_T1 + n];
        const float bias = lb[0];
        const float4 t2 = *(const float4*)(ws + OFF_T2 + 4 * i4);
        float lgx = t1n + t2.x + tt.x + bias;
        float lgy = t1n + t2.y + tt.y + bias;
        float lgz = t1n + t2.z + tt.z + bias;
        float lgw = t1n + t2.w + tt.w + bias;
        float bc;
        if (wv < 2)
            bc = softplus_f(-lgx) + softplus_f(-lgy) + softplus_f(-lgz) + softplus_f(-lgw);
        else
            bc = softplus_f(lgx) + softplus_f(lgy) + softplus_f(lgz) + softplus_f(lgw);
        part += bc * (1.f / 1024.f);

        #pragma unroll
        for (int off = 32; off; off >>= 1) part += __shfl_xor(part, off);
        if (l == 0) fin[4 + wv] = part;
        __syncthreads();
        if (tid == 0)
            atomicAdd(out, fin[4] + fin[5] + fin[6] + fin[7]);
    }
}

extern "C" void kernel_launch(void* const* d_in, const int* in_sizes, int n_in,
                              void* d_out, int out_size, void* d_ws, size_t ws_size,
                              hipStream_t stream) {
    (void)in_sizes; (void)n_in; (void)out_size; (void)ws_size;
    const float* pos = (const float*)d_in[0];
    const float* neg = (const float*)d_in[1];
    const float* w   = (const float*)d_in[2];
    const float* lb  = (const float*)d_in[3];
    float* out = (float*)d_out;
    float* ws  = (float*)d_ws;

    mono_kernel<<<512, 256, 0, stream>>>(pos, neg, w, lb, ws, out);
}